// Round 15
// baseline (142.352 us; speedup 1.0000x reference)
//
#include <hip/hip_runtime.h>

// ---------------- problem constants (fixed by reference) ----------------
#define T_DIM 110
#define B_DIM 256
#define D_DIM 512
#define H_DIM 512
#define K_CAT 1024              // K layout: interleaved (fr0,fi0,fr1,fi1,...)
#define M_DIM (T_DIM * B_DIM)   // 28160
#define BD    (B_DIM * D_DIM)   // 131072

typedef float f32x4 __attribute__((ext_vector_type(4)));
typedef short bf16x8 __attribute__((ext_vector_type(8)));

static __device__ __forceinline__ unsigned short f2bf(float f) {
    unsigned u = __builtin_bit_cast(unsigned, f);
    u += 0x7fffu + ((u >> 16) & 1u);      // round-to-nearest-even
    return (unsigned short)(u >> 16);
}

// ---------------- kernel 1: fused prep (weights + bias + turn table) ----------
__global__ __launch_bounds__(256) void prep_all_kernel(
    const float* __restrict__ W1, const float* __restrict__ b1,
    const float* __restrict__ W2,
    const float* __restrict__ turna, const float* __restrict__ turnb,
    unsigned short* __restrict__ Bt,   // [H][K_CAT] bf16
    float* __restrict__ bias2,         // [H]
    float4* __restrict__ TT)           // [T][D]
{
    int i = blockIdx.x * 256 + threadIdx.x;
    if (i < H_DIM) bias2[i] = 2.0f * b1[i];
    if (i < T_DIM * D_DIM) {
        float s1, c1, s2, c2;
        __sincosf(turna[i], &s1, &c1);
        __sincosf(turnb[i], &s2, &c2);
        TT[i] = make_float4(c1, s1, c2, s2);
    }
    if (i < H_DIM * K_CAT) {
        int h = i / K_CAT;
        int k = i % K_CAT;
        int j = k >> 1;
        float w = (k & 1) ? (W1[h * D_DIM + j] - W2[h * D_DIM + j])
                          : (W1[h * D_DIM + j] + W2[h * D_DIM + j]);
        Bt[i] = f2bf(w);
    }
}

// ---------------- kernel 2: chain-split features + scan (TLP x2) --------------
// R14 post-mortem: burst banks held registers (VGPR 56) but 2 waves/SIMD can't
// hide latency. Fix = TLP: grid x2 on a chain axis (1024 blocks, 4 waves/SIMD).
// Each block walks ALL t with R14's burst-banked UNCONDITIONAL loads (the
// structure that provably keeps VGPRs), but compute/update/store is wrapped in
// a block-uniform if(own): chain c processes only its speaker's steps (~55),
// tracking a single (pr,pi). Exactly one chain writes each A32[t] (the owner);
// gate=0 at t==0 gives temp0=f0 and non-owner keeps (1,1) until its first
// owned step — numerically identical to R11/R13 (absmax 0.03125). Twin blocks
// re-read a/v/l; L3 (256MB) holds the 173MB set so HBM stays ~flat.
__global__ __launch_bounds__(256, 1) void feat_scan_kernel(
    const float* __restrict__ a, const float* __restrict__ v,
    const float* __restrict__ l, const float* __restrict__ qmask,
    const float* __restrict__ mu_a, const float* __restrict__ mu_v,
    const float* __restrict__ mu_l,
    const float* __restrict__ shifta, const float* __restrict__ shiftv,
    const float4* __restrict__ TT,
    unsigned int* __restrict__ A32)    // [M][K_CAT/2] dwords (fr|fi<<16)
{
    __shared__ float qm_s[T_DIM], mua_s[T_DIM], muv_s[T_DIM], mul_s[T_DIM];
    const int bid   = blockIdx.x;          // 1024 blocks
    const int b     = bid >> 2;
    const int dhalf = (bid >> 1) & 1;
    const bool chain0 = (bid & 1) == 0;    // true: speaker-A chain
    const int tx = threadIdx.x;
    const int d  = (dhalf << 8) + tx;
    if (tx < T_DIM) {
        qm_s[tx]  = qmask[(size_t)(tx * B_DIM + b) * 2];
        mua_s[tx] = mu_a[tx];
        muv_s[tx] = mu_v[tx];
        mul_s[tx] = mu_l[tx];
    }
    const float sa = shifta[d];
    const float sv = shiftv[d];
    __syncthreads();

    const size_t gbase = (size_t)b * D_DIM + d;

#define LOADSLOT(SA_, SV_, SL_, ST_, tt_)                                      \
    { const int tc = (tt_) <= T_DIM - 1 ? (tt_) : T_DIM - 1;                   \
      SA_ = a[(size_t)tc * BD + gbase];                                        \
      SV_ = v[(size_t)tc * BD + gbase];                                        \
      SL_ = l[(size_t)tc * BD + gbase];                                        \
      ST_ = TT[(size_t)tc * D_DIM + d]; }

    // bank A: t % 8 in 0..3;  bank B: t % 8 in 4..7
    float  a0,v0,l0, a1,v1,l1, a2,v2,l2, a3,v3,l3;
    float4 t0,t1,t2,t3;
    float  a4,v4,l4, a5,v5,l5, a6,v6,l6, a7,v7,l7;
    float4 t4,t5,t6,t7;

    LOADSLOT(a0,v0,l0,t0, 0)  LOADSLOT(a1,v1,l1,t1, 1)
    LOADSLOT(a2,v2,l2,t2, 2)  LOADSLOT(a3,v3,l3,t3, 3)
    LOADSLOT(a4,v4,l4,t4, 4)  LOADSLOT(a5,v5,l5,t5, 5)
    LOADSLOT(a6,v6,l6,t6, 6)  LOADSLOT(a7,v7,l7,t7, 7)

    // single-chain state; (1,1) pre-init == reference's non-owner init.
    float pr = 1.f, pi = 1.f;

// guarded compute step: runs only on this chain's owned t (block-uniform).
#define ITER(tt_, SA_, SV_, SL_, ST_)                                          \
    {                                                                          \
        const int t_ = (tt_);                                                  \
        const bool own = (qm_s[t_] > 0.5f) == chain0;                          \
        if (own) {                                                             \
            const float ma = mua_s[t_], mv = muv_s[t_], ml = mul_s[t_];        \
            float sA, cA, sV, cV, sL, cL;                                      \
            __sincosf(SA_ + sa, &sA, &cA);                                     \
            __sincosf(SV_ + sv, &sV, &cV);                                     \
            __sincosf(SL_,      &sL, &cL);                                     \
            float fr = ml * cL + ma * cA + mv * cV;                            \
            float fi = ml * sL + ma * sA + mv * sV;                            \
            const float cp = chain0 ? ST_.x : ST_.z;                           \
            const float sp = chain0 ? ST_.y : ST_.w;                           \
            const float tr = pr * cp - pi * sp;                                \
            const float ti = pr * sp + pi * cp;                                \
            const float gate = (t_ == 0) ? 0.0f : 1.0f;                        \
            const float m2 = fmaxf(tr * tr + ti * ti, 1e-30f);                 \
            const float inv = gate * __builtin_amdgcn_rsqf(m2);                \
            fr += tr * inv;                                                    \
            fi += ti * inv;                                                    \
            pr = fr; pi = fi;                                                  \
            A32[(size_t)(t_ * B_DIM + b) * (K_CAT / 2) + d] =                  \
                (unsigned)f2bf(fr) | ((unsigned)f2bf(fi) << 16);               \
        }                                                                      \
    }

    // main loop: 13 groups of 8 (t = 0..103)
    for (int g = 0; g < 104; g += 8) {
        ITER(g + 0, a0, v0, l0, t0)
        ITER(g + 1, a1, v1, l1, t1)
        ITER(g + 2, a2, v2, l2, t2)
        ITER(g + 3, a3, v3, l3, t3)
        LOADSLOT(a0,v0,l0,t0, g + 8)
        LOADSLOT(a1,v1,l1,t1, g + 9)
        LOADSLOT(a2,v2,l2,t2, g + 10)
        LOADSLOT(a3,v3,l3,t3, g + 11)
        __builtin_amdgcn_sched_barrier(0x387);   // VMEM may not cross

        ITER(g + 4, a4, v4, l4, t4)
        ITER(g + 5, a5, v5, l5, t5)
        ITER(g + 6, a6, v6, l6, t6)
        ITER(g + 7, a7, v7, l7, t7)
        LOADSLOT(a4,v4,l4,t4, g + 12)
        LOADSLOT(a5,v5,l5,t5, g + 13)
        LOADSLOT(a6,v6,l6,t6, g + 14)
        LOADSLOT(a7,v7,l7,t7, g + 15)
        __builtin_amdgcn_sched_barrier(0x387);
    }
    // epilogue: bank A holds t=104..107, bank B slots 0,1 hold t=108,109.
    ITER(104, a0, v0, l0, t0)
    ITER(105, a1, v1, l1, t1)
    ITER(106, a2, v2, l2, t2)
    ITER(107, a3, v3, l3, t3)
    ITER(108, a4, v4, l4, t4)
    ITER(109, a5, v5, l5, t5)
#undef ITER
#undef LOADSLOT
}

// ---------------- kernel 3: bf16 MFMA GEMM  C = A @ Bt^T + bias ---------------
// Proven 1-phase m97 structure (~30 us = its compute ceiling for 29.5 GFLOP).
#define BM 128
#define BN 128
#define BK 64

__global__ __launch_bounds__(256) void gemm_kernel(
    const unsigned short* __restrict__ A,
    const unsigned short* __restrict__ Bt,
    const float* __restrict__ bias2,
    float* __restrict__ C)
{
    __shared__ __align__(16) unsigned short As[BM * BK];   // 16 KB, linear
    __shared__ __align__(16) unsigned short Bs[BN * BK];   // 16 KB, linear

    const int tid = threadIdx.x;
    const int wave = tid >> 6;
    const int lane = tid & 63;
    const int wr = wave >> 1;          // 0..1 (M dir)
    const int wc = wave & 1;           // 0..1 (N dir)
    const int m0 = blockIdx.x * BM;
    const int n0 = blockIdx.y * BN;
    const int lrow = lane & 15;
    const int lk8 = (lane >> 4) * 8;   // k-offset of this lane's 8 elements

    const int srow = wave * 32;        // first row this wave stages
    const int lrow8 = lane >> 3;       // row within 8-row group
    const int lchunk = lane & 7;       // 16B chunk within row

    f32x4 acc[4][4] = {};

    for (int k0 = 0; k0 < K_CAT; k0 += BK) {
        #pragma unroll
        for (int c = 0; c < 4; ++c) {
            const int row = srow + c * 8 + lrow8;
            {
                const unsigned short* gp = A + (size_t)(m0 + row) * K_CAT + k0 + lchunk * 8;
                unsigned short* lp = As + (srow + c * 8) * BK + lane * 8;
                __builtin_amdgcn_global_load_lds(
                    (const __attribute__((address_space(1))) unsigned int*)gp,
                    (__attribute__((address_space(3))) unsigned int*)lp,
                    16, 0, 0);
            }
            {
                const unsigned short* gp = Bt + (size_t)(n0 + row) * K_CAT + k0 + lchunk * 8;
                unsigned short* lp = Bs + (srow + c * 8) * BK + lane * 8;
                __builtin_amdgcn_global_load_lds(
                    (const __attribute__((address_space(1))) unsigned int*)gp,
                    (__attribute__((address_space(3))) unsigned int*)lp,
                    16, 0, 0);
            }
        }
        __syncthreads();

        bf16x8 af[4][2], bfv[4][2];
        #pragma unroll
        for (int m = 0; m < 4; ++m)
            #pragma unroll
            for (int kk = 0; kk < 2; ++kk)
                af[m][kk] = *reinterpret_cast<const bf16x8*>(
                    &As[(wr * 64 + m * 16 + lrow) * BK + kk * 32 + lk8]);
        #pragma unroll
        for (int n = 0; n < 4; ++n)
            #pragma unroll
            for (int kk = 0; kk < 2; ++kk)
                bfv[n][kk] = *reinterpret_cast<const bf16x8*>(
                    &Bs[(wc * 64 + n * 16 + lrow) * BK + kk * 32 + lk8]);

        #pragma unroll
        for (int kk = 0; kk < 2; ++kk)
            #pragma unroll
            for (int m = 0; m < 4; ++m)
                #pragma unroll
                for (int n = 0; n < 4; ++n)
                    acc[m][n] = __builtin_amdgcn_mfma_f32_16x16x32_bf16(
                        af[m][kk], bfv[n][kk], acc[m][n], 0, 0, 0);
        __syncthreads();
    }

    // -------- epilogue: C/D layout col=lane&15, row=(lane>>4)*4+r  (m89/m91)
    const int rbase = m0 + wr * 64 + (lane >> 4) * 4;
    const int cbase = n0 + wc * 64;
    #pragma unroll
    for (int n = 0; n < 4; ++n) {
        const int col = cbase + n * 16 + lrow;
        const float bv = bias2[col];
        #pragma unroll
        for (int m = 0; m < 4; ++m) {
            const int row0 = rbase + m * 16;
            #pragma unroll
            for (int r = 0; r < 4; ++r) {
                C[(size_t)(row0 + r) * H_DIM + col] = acc[m][n][r] + bv;
            }
        }
    }
}

// ---------------- launcher ----------------
extern "C" void kernel_launch(void* const* d_in, const int* in_sizes, int n_in,
                              void* d_out, int out_size, void* d_ws, size_t ws_size,
                              hipStream_t stream) {
    const float* a      = (const float*)d_in[0];
    const float* v      = (const float*)d_in[1];
    const float* l      = (const float*)d_in[2];
    const float* qmask  = (const float*)d_in[3];
    // d_in[4] umask: unused by reference
    const float* mu_a   = (const float*)d_in[5];
    const float* mu_v   = (const float*)d_in[6];
    const float* mu_l   = (const float*)d_in[7];
    const float* shifta = (const float*)d_in[8];
    const float* shiftv = (const float*)d_in[9];
    const float* turna  = (const float*)d_in[10];
    const float* turnb  = (const float*)d_in[11];
    const float* W1     = (const float*)d_in[12];
    const float* b1     = (const float*)d_in[13];
    const float* W2     = (const float*)d_in[14];
    // d_in[15] b2: cancels in xr+xi
    float* out = (float*)d_out;

    char* ws = (char*)d_ws;
    unsigned short* Afeat = (unsigned short*)ws;                       // M*K_CAT bf16
    size_t offB  = (size_t)M_DIM * K_CAT * sizeof(unsigned short);     // 57.7 MB
    unsigned short* Bt = (unsigned short*)(ws + offB);                 // H*K_CAT bf16
    size_t offBias = offB + (size_t)H_DIM * K_CAT * sizeof(unsigned short);
    float* bias2 = (float*)(ws + offBias);
    size_t offTT = offBias + 4096;
    float4* TT = (float4*)(ws + offTT);                                // T*D float4

    prep_all_kernel<<<(H_DIM * K_CAT + 255) / 256, 256, 0, stream>>>(
        W1, b1, W2, turna, turnb, Bt, bias2, TT);
    feat_scan_kernel<<<B_DIM * 4, 256, 0, stream>>>(
        a, v, l, qmask, mu_a, mu_v, mu_l, shifta, shiftv, TT, (unsigned int*)Afeat);
    dim3 grid(M_DIM / BM, H_DIM / BN);
    gemm_kernel<<<grid, 256, 0, stream>>>(Afeat, Bt, bias2, out);
}

// Round 16
// 126.066 us; speedup vs baseline: 1.1292x; 1.1292x over previous
//
#include <hip/hip_runtime.h>

// ---------------- problem constants (fixed by reference) ----------------
#define T_DIM 110
#define B_DIM 256
#define D_DIM 512
#define H_DIM 512
#define K_CAT 1024              // K layout: interleaved (fr0,fi0,fr1,fi1,...)
#define M_DIM (T_DIM * B_DIM)   // 28160
#define BD    (B_DIM * D_DIM)   // 131072

typedef float f32x4 __attribute__((ext_vector_type(4)));
typedef short bf16x8 __attribute__((ext_vector_type(8)));

static __device__ __forceinline__ unsigned short f2bf(float f) {
    unsigned u = __builtin_bit_cast(unsigned, f);
    u += 0x7fffu + ((u >> 16) & 1u);      // round-to-nearest-even
    return (unsigned short)(u >> 16);
}
static __device__ __forceinline__ unsigned short f2h(float f) {
    return __builtin_bit_cast(unsigned short, (_Float16)f);   // v_cvt_f16_f32 RNE
}
static __device__ __forceinline__ float h2f(unsigned short h) {
    return (float)__builtin_bit_cast(_Float16, h);
}

// ---------------- kernel 1: fused prep (weights + bias + turn table) ----------
__global__ __launch_bounds__(256) void prep_all_kernel(
    const float* __restrict__ W1, const float* __restrict__ b1,
    const float* __restrict__ W2,
    const float* __restrict__ turna, const float* __restrict__ turnb,
    unsigned short* __restrict__ Bt,   // [H][K_CAT] bf16
    float* __restrict__ bias2,         // [H]
    float4* __restrict__ TT)           // [T][D]
{
    int i = blockIdx.x * 256 + threadIdx.x;
    if (i < H_DIM) bias2[i] = 2.0f * b1[i];
    if (i < T_DIM * D_DIM) {
        float s1, c1, s2, c2;
        __sincosf(turna[i], &s1, &c1);
        __sincosf(turnb[i], &s2, &c2);
        TT[i] = make_float4(c1, s1, c2, s2);
    }
    if (i < H_DIM * K_CAT) {
        int h = i / K_CAT;
        int k = i % K_CAT;
        int j = k >> 1;
        float w = (k & 1) ? (W1[h * D_DIM + j] - W2[h * D_DIM + j])
                          : (W1[h * D_DIM + j] + W2[h * D_DIM + j]);
        Bt[i] = f2bf(w);
    }
}

// ---------------- kernel 2a: features (fully parallel) -> A32 as f16 pairs -----
// R5 structure with the precision fix: intermediate features stored as F16
// (2^-11 mantissa, 8x finer than the bf16 that failed marginally at 0.186) in
// the SAME dwords the scan will overwrite with bf16 — in-place, no extra ws.
// Thread = 2 consecutive d of one row. BW-bound at full occupancy.
__global__ __launch_bounds__(256) void feat_kernel(
    const float* __restrict__ a, const float* __restrict__ v,
    const float* __restrict__ l,
    const float* __restrict__ mu_a, const float* __restrict__ mu_v,
    const float* __restrict__ mu_l,
    const float* __restrict__ shifta, const float* __restrict__ shiftv,
    unsigned int* __restrict__ A32)    // [M][512] dwords
{
    const int tid = blockIdx.x * 256 + threadIdx.x;  // 0 .. M*D/2-1 (exact grid)
    const int row = tid >> 8;            // 256 threads per row
    const int d2  = (tid & 255) << 1;    // even d
    const int t   = row >> 8;            // row = t*256 + b
    const size_t g = (size_t)row * D_DIM + d2;

    const float2 av = *reinterpret_cast<const float2*>(a + g);
    const float2 vv = *reinterpret_cast<const float2*>(v + g);
    const float2 lv = *reinterpret_cast<const float2*>(l + g);
    const float2 sa = *reinterpret_cast<const float2*>(shifta + d2);
    const float2 sv = *reinterpret_cast<const float2*>(shiftv + d2);
    const float ma = mu_a[t], mv = mu_v[t], ml = mu_l[t];

    uint2 outw;
    {
        float sA, cA, sV, cV, sL, cL;
        __sincosf(av.x + sa.x, &sA, &cA);
        __sincosf(vv.x + sv.x, &sV, &cV);
        __sincosf(lv.x,        &sL, &cL);
        const float fr = ml * cL + ma * cA + mv * cV;
        const float fi = ml * sL + ma * sA + mv * sV;
        outw.x = (unsigned)f2h(fr) | ((unsigned)f2h(fi) << 16);
    }
    {
        float sA, cA, sV, cV, sL, cL;
        __sincosf(av.y + sa.y, &sA, &cA);
        __sincosf(vv.y + sv.y, &sV, &cV);
        __sincosf(lv.y,        &sL, &cL);
        const float fr = ml * cL + ma * cA + mv * cV;
        const float fi = ml * sL + ma * sA + mv * sV;
        outw.y = (unsigned)f2h(fr) | ((unsigned)f2h(fi) << 16);
    }
    *reinterpret_cast<uint2*>(A32 + (size_t)row * (K_CAT / 2) + d2) = outw;
}

// ---------------- kernel 2b: scan (serial over t), IN PLACE on A32 -------------
// Thread = one (b,d). Per step: read its own dword (f16 features), run the
// recurrence, overwrite the same dword with bf16 — no cross-thread aliasing,
// no barriers. No sincos/mu in the loop (moved to feat pass). R14 burst-bank
// structure (proven to hold VGPRs): two 4-slot banks, burst refills between
// compute half-groups, sched_barrier(0x387) pins only VMEM.
__global__ __launch_bounds__(256, 1) void scan_kernel(
    const float* __restrict__ qmask,
    const float4* __restrict__ TT,
    unsigned int* __restrict__ A32)
{
    __shared__ float qm_s[T_DIM];
    const int tx = threadIdx.x;
    const int b  = blockIdx.x >> 1;
    const int d  = ((blockIdx.x & 1) << 8) + tx;
    if (tx < T_DIM) qm_s[tx] = qmask[(size_t)(tx * B_DIM + b) * 2];
    __syncthreads();

#define AIDX(t_) ((size_t)((t_) * B_DIM + b) * (K_CAT / 2) + d)

#define LOADSLOT(FP_, ST_, tt_)                                                \
    { const int tc = (tt_) <= T_DIM - 1 ? (tt_) : T_DIM - 1;                   \
      FP_ = A32[AIDX(tc)];                                                     \
      ST_ = TT[(size_t)tc * D_DIM + d]; }

    // bank A: t % 8 in 0..3;  bank B: t % 8 in 4..7
    unsigned f0, f1, f2, f3, f4, f5, f6, f7;
    float4   t0, t1, t2, t3, t4, t5, t6, t7;

    LOADSLOT(f0, t0, 0)  LOADSLOT(f1, t1, 1)
    LOADSLOT(f2, t2, 2)  LOADSLOT(f3, t3, 3)
    LOADSLOT(f4, t4, 4)  LOADSLOT(f5, t5, 5)
    LOADSLOT(f6, t6, 6)  LOADSLOT(f7, t7, 7)

    // pre-init (1,1): with gate=0 at t=0 the generic select reproduces the
    // reference's t=0 rule exactly.
    float pAr = 1.f, pAi = 1.f, pBr = 1.f, pBi = 1.f;

#define ITER(tt_, FP_, ST_)                                                    \
    {                                                                          \
        const int t_ = (tt_);                                                  \
        float fr = h2f((unsigned short)(FP_ & 0xffffu));                       \
        float fi = h2f((unsigned short)(FP_ >> 16));                           \
        const bool isA = qm_s[t_] > 0.5f;                                      \
        const float cp = isA ? ST_.x : ST_.z;                                  \
        const float sp = isA ? ST_.y : ST_.w;                                  \
        const float pr = isA ? pAr : pBr;                                      \
        const float pi = isA ? pAi : pBi;                                      \
        const float tr = pr * cp - pi * sp;                                    \
        const float ti = pr * sp + pi * cp;                                    \
        const float gate = (t_ == 0) ? 0.0f : 1.0f;                            \
        const float m2 = fmaxf(tr * tr + ti * ti, 1e-30f);                     \
        const float inv = gate * __builtin_amdgcn_rsqf(m2);                    \
        fr += tr * inv;                                                        \
        fi += ti * inv;                                                        \
        pAr = isA ? fr : pAr;  pAi = isA ? fi : pAi;                           \
        pBr = isA ? pBr : fr;  pBi = isA ? pBi : fi;                           \
        A32[AIDX(t_)] = (unsigned)f2bf(fr) | ((unsigned)f2bf(fi) << 16);       \
    }

    // main loop: 13 groups of 8 (t = 0..103). Burst refills read t+8..t+15,
    // which this thread has NOT yet overwritten (still f16 from feat pass).
    for (int g = 0; g < 104; g += 8) {
        ITER(g + 0, f0, t0)
        ITER(g + 1, f1, t1)
        ITER(g + 2, f2, t2)
        ITER(g + 3, f3, t3)
        LOADSLOT(f0, t0, g + 8)
        LOADSLOT(f1, t1, g + 9)
        LOADSLOT(f2, t2, g + 10)
        LOADSLOT(f3, t3, g + 11)
        __builtin_amdgcn_sched_barrier(0x387);   // VMEM may not cross

        ITER(g + 4, f4, t4)
        ITER(g + 5, f5, t5)
        ITER(g + 6, f6, t6)
        ITER(g + 7, f7, t7)
        LOADSLOT(f4, t4, g + 12)
        LOADSLOT(f5, t5, g + 13)
        LOADSLOT(f6, t6, g + 14)
        LOADSLOT(f7, t7, g + 15)
        __builtin_amdgcn_sched_barrier(0x387);
    }
    // epilogue: bank A holds t=104..107; bank B slots 0,1 hold t=108,109
    // (slots 2,3 are clamped duplicates, never consumed).
    ITER(104, f0, t0)
    ITER(105, f1, t1)
    ITER(106, f2, t2)
    ITER(107, f3, t3)
    ITER(108, f4, t4)
    ITER(109, f5, t5)
#undef ITER
#undef LOADSLOT
#undef AIDX
}

// ---------------- kernel 3: bf16 MFMA GEMM  C = A @ Bt^T + bias ---------------
// Proven 1-phase m97 structure (~30 us): 128x128 tile, BK=64, global_load_lds
// width-16 into linear LDS (32 KB), 4 waves (2x2), 4x4 frags of 16x16x32.
#define BM 128
#define BN 128
#define BK 64

__global__ __launch_bounds__(256) void gemm_kernel(
    const unsigned short* __restrict__ A,
    const unsigned short* __restrict__ Bt,
    const float* __restrict__ bias2,
    float* __restrict__ C)
{
    __shared__ __align__(16) unsigned short As[BM * BK];   // 16 KB, linear
    __shared__ __align__(16) unsigned short Bs[BN * BK];   // 16 KB, linear

    const int tid = threadIdx.x;
    const int wave = tid >> 6;
    const int lane = tid & 63;
    const int wr = wave >> 1;          // 0..1 (M dir)
    const int wc = wave & 1;           // 0..1 (N dir)
    const int m0 = blockIdx.x * BM;
    const int n0 = blockIdx.y * BN;
    const int lrow = lane & 15;
    const int lk8 = (lane >> 4) * 8;   // k-offset of this lane's 8 elements

    const int srow = wave * 32;        // first row this wave stages
    const int lrow8 = lane >> 3;       // row within 8-row group
    const int lchunk = lane & 7;       // 16B chunk within row

    f32x4 acc[4][4] = {};

    for (int k0 = 0; k0 < K_CAT; k0 += BK) {
        #pragma unroll
        for (int c = 0; c < 4; ++c) {
            const int row = srow + c * 8 + lrow8;
            {
                const unsigned short* gp = A + (size_t)(m0 + row) * K_CAT + k0 + lchunk * 8;
                unsigned short* lp = As + (srow + c * 8) * BK + lane * 8;
                __builtin_amdgcn_global_load_lds(
                    (const __attribute__((address_space(1))) unsigned int*)gp,
                    (__attribute__((address_space(3))) unsigned int*)lp,
                    16, 0, 0);
            }
            {
                const unsigned short* gp = Bt + (size_t)(n0 + row) * K_CAT + k0 + lchunk * 8;
                unsigned short* lp = Bs + (srow + c * 8) * BK + lane * 8;
                __builtin_amdgcn_global_load_lds(
                    (const __attribute__((address_space(1))) unsigned int*)gp,
                    (__attribute__((address_space(3))) unsigned int*)lp,
                    16, 0, 0);
            }
        }
        __syncthreads();

        bf16x8 af[4][2], bfv[4][2];
        #pragma unroll
        for (int m = 0; m < 4; ++m)
            #pragma unroll
            for (int kk = 0; kk < 2; ++kk)
                af[m][kk] = *reinterpret_cast<const bf16x8*>(
                    &As[(wr * 64 + m * 16 + lrow) * BK + kk * 32 + lk8]);
        #pragma unroll
        for (int n = 0; n < 4; ++n)
            #pragma unroll
            for (int kk = 0; kk < 2; ++kk)
                bfv[n][kk] = *reinterpret_cast<const bf16x8*>(
                    &Bs[(wc * 64 + n * 16 + lrow) * BK + kk * 32 + lk8]);

        #pragma unroll
        for (int kk = 0; kk < 2; ++kk)
            #pragma unroll
            for (int m = 0; m < 4; ++m)
                #pragma unroll
                for (int n = 0; n < 4; ++n)
                    acc[m][n] = __builtin_amdgcn_mfma_f32_16x16x32_bf16(
                        af[m][kk], bfv[n][kk], acc[m][n], 0, 0, 0);
        __syncthreads();
    }

    // -------- epilogue: C/D layout col=lane&15, row=(lane>>4)*4+r  (m89/m91)
    const int rbase = m0 + wr * 64 + (lane >> 4) * 4;
    const int cbase = n0 + wc * 64;
    #pragma unroll
    for (int n = 0; n < 4; ++n) {
        const int col = cbase + n * 16 + lrow;
        const float bv = bias2[col];
        #pragma unroll
        for (int m = 0; m < 4; ++m) {
            const int row0 = rbase + m * 16;
            #pragma unroll
            for (int r = 0; r < 4; ++r) {
                C[(size_t)(row0 + r) * H_DIM + col] = acc[m][n][r] + bv;
            }
        }
    }
}

// ---------------- launcher ----------------
extern "C" void kernel_launch(void* const* d_in, const int* in_sizes, int n_in,
                              void* d_out, int out_size, void* d_ws, size_t ws_size,
                              hipStream_t stream) {
    const float* a      = (const float*)d_in[0];
    const float* v      = (const float*)d_in[1];
    const float* l      = (const float*)d_in[2];
    const float* qmask  = (const float*)d_in[3];
    // d_in[4] umask: unused by reference
    const float* mu_a   = (const float*)d_in[5];
    const float* mu_v   = (const float*)d_in[6];
    const float* mu_l   = (const float*)d_in[7];
    const float* shifta = (const float*)d_in[8];
    const float* shiftv = (const float*)d_in[9];
    const float* turna  = (const float*)d_in[10];
    const float* turnb  = (const float*)d_in[11];
    const float* W1     = (const float*)d_in[12];
    const float* b1     = (const float*)d_in[13];
    const float* W2     = (const float*)d_in[14];
    // d_in[15] b2: cancels in xr+xi
    float* out = (float*)d_out;

    char* ws = (char*)d_ws;
    unsigned short* Afeat = (unsigned short*)ws;                       // M*K_CAT bf16
    size_t offB  = (size_t)M_DIM * K_CAT * sizeof(unsigned short);     // 57.7 MB
    unsigned short* Bt = (unsigned short*)(ws + offB);                 // H*K_CAT bf16
    size_t offBias = offB + (size_t)H_DIM * K_CAT * sizeof(unsigned short);
    float* bias2 = (float*)(ws + offBias);
    size_t offTT = offBias + 4096;
    float4* TT = (float4*)(ws + offTT);                                // T*D float4

    prep_all_kernel<<<(H_DIM * K_CAT + 255) / 256, 256, 0, stream>>>(
        W1, b1, W2, turna, turnb, Bt, bias2, TT);
    feat_kernel<<<(M_DIM * D_DIM / 2) / 256, 256, 0, stream>>>(
        a, v, l, mu_a, mu_v, mu_l, shifta, shiftv, (unsigned int*)Afeat);
    scan_kernel<<<B_DIM * 2, 256, 0, stream>>>(
        qmask, TT, (unsigned int*)Afeat);
    dim3 grid(M_DIM / BM, H_DIM / BN);
    gemm_kernel<<<grid, 256, 0, stream>>>(Afeat, Bt, bias2, out);
}

// Round 17
// 123.694 us; speedup vs baseline: 1.1508x; 1.0192x over previous
//
#include <hip/hip_runtime.h>

// ---------------- problem constants (fixed by reference) ----------------
#define T_DIM 110
#define B_DIM 256
#define D_DIM 512
#define H_DIM 512
#define K_CAT 1024              // K layout: interleaved (fr0,fi0,fr1,fi1,...)
#define M_DIM (T_DIM * B_DIM)   // 28160
#define BD    (B_DIM * D_DIM)   // 131072

typedef float f32x4 __attribute__((ext_vector_type(4)));
typedef short bf16x8 __attribute__((ext_vector_type(8)));

static __device__ __forceinline__ unsigned short f2bf(float f) {
    unsigned u = __builtin_bit_cast(unsigned, f);
    u += 0x7fffu + ((u >> 16) & 1u);      // round-to-nearest-even
    return (unsigned short)(u >> 16);
}
static __device__ __forceinline__ unsigned short f2h(float f) {
    return __builtin_bit_cast(unsigned short, (_Float16)f);   // v_cvt_f16_f32 RNE
}
static __device__ __forceinline__ float h2f(unsigned short h) {
    return (float)__builtin_bit_cast(_Float16, h);
}

// ---------------- kernel 1: fused prep (weights + bias + turn table) ----------
__global__ __launch_bounds__(256) void prep_all_kernel(
    const float* __restrict__ W1, const float* __restrict__ b1,
    const float* __restrict__ W2,
    const float* __restrict__ turna, const float* __restrict__ turnb,
    unsigned short* __restrict__ Bt,   // [H][K_CAT] bf16
    float* __restrict__ bias2,         // [H]
    float4* __restrict__ TT)           // [T][D]
{
    int i = blockIdx.x * 256 + threadIdx.x;
    if (i < H_DIM) bias2[i] = 2.0f * b1[i];
    if (i < T_DIM * D_DIM) {
        float s1, c1, s2, c2;
        __sincosf(turna[i], &s1, &c1);
        __sincosf(turnb[i], &s2, &c2);
        TT[i] = make_float4(c1, s1, c2, s2);
    }
    if (i < H_DIM * K_CAT) {
        int h = i / K_CAT;
        int k = i % K_CAT;
        int j = k >> 1;
        float w = (k & 1) ? (W1[h * D_DIM + j] - W2[h * D_DIM + j])
                          : (W1[h * D_DIM + j] + W2[h * D_DIM + j]);
        Bt[i] = f2bf(w);
    }
}

// ---------------- kernel 2a: features (fully parallel) -> A32 as f16 pairs -----
// R16 post-mortem: feat at 29% HBM with float2 loads = G13 under-vectorization.
// Now float4 loads (16B/lane sweet spot), 4 d's per thread, uint4 store.
// F16 intermediate (2^-11) written in the SAME dwords the scan overwrites with
// bf16 — in-place, no extra ws. Numerics per element unchanged from R16
// (absmax 0.0596 <= 0.175).
__global__ __launch_bounds__(256) void feat_kernel(
    const float* __restrict__ a, const float* __restrict__ v,
    const float* __restrict__ l,
    const float* __restrict__ mu_a, const float* __restrict__ mu_v,
    const float* __restrict__ mu_l,
    const float* __restrict__ shifta, const float* __restrict__ shiftv,
    unsigned int* __restrict__ A32)    // [M][512] dwords
{
    const int tid = blockIdx.x * 256 + threadIdx.x;  // 0 .. M*D/4-1 (exact grid)
    const int row = tid >> 7;            // 128 threads per row
    const int d4  = (tid & 127) << 2;    // d, d+1, d+2, d+3
    const int t   = row >> 8;            // row = t*256 + b
    const size_t g = (size_t)row * D_DIM + d4;

    const float4 av = *reinterpret_cast<const float4*>(a + g);
    const float4 vv = *reinterpret_cast<const float4*>(v + g);
    const float4 lv = *reinterpret_cast<const float4*>(l + g);
    const float4 sa = *reinterpret_cast<const float4*>(shifta + d4);
    const float4 sv = *reinterpret_cast<const float4*>(shiftv + d4);
    const float ma = mu_a[t], mv = mu_v[t], ml = mu_l[t];

    const float aj[4] = {av.x, av.y, av.z, av.w};
    const float vj[4] = {vv.x, vv.y, vv.z, vv.w};
    const float lj[4] = {lv.x, lv.y, lv.z, lv.w};
    const float saj[4] = {sa.x, sa.y, sa.z, sa.w};
    const float svj[4] = {sv.x, sv.y, sv.z, sv.w};
    unsigned outw[4];
    #pragma unroll
    for (int j = 0; j < 4; ++j) {
        float sA, cA, sV, cV, sL, cL;
        __sincosf(aj[j] + saj[j], &sA, &cA);
        __sincosf(vj[j] + svj[j], &sV, &cV);
        __sincosf(lj[j],          &sL, &cL);
        const float fr = ml * cL + ma * cA + mv * cV;
        const float fi = ml * sL + ma * sA + mv * sV;
        outw[j] = (unsigned)f2h(fr) | ((unsigned)f2h(fi) << 16);
    }
    uint4 o = make_uint4(outw[0], outw[1], outw[2], outw[3]);
    *reinterpret_cast<uint4*>(A32 + (size_t)row * (K_CAT / 2) + d4) = o;
}

// ---------------- kernel 2b: scan (serial over t), IN PLACE on A32 -------------
// (R16 version, verbatim — passed at absmax 0.0596.) Thread = one (b,d). Per
// step: read own dword (f16 features), run recurrence, overwrite with bf16.
// No cross-thread aliasing, no barriers. R14 burst-bank structure; directional
// sched_barrier(0x387) pins only VMEM.
__global__ __launch_bounds__(256, 1) void scan_kernel(
    const float* __restrict__ qmask,
    const float4* __restrict__ TT,
    unsigned int* __restrict__ A32)
{
    __shared__ float qm_s[T_DIM];
    const int tx = threadIdx.x;
    const int b  = blockIdx.x >> 1;
    const int d  = ((blockIdx.x & 1) << 8) + tx;
    if (tx < T_DIM) qm_s[tx] = qmask[(size_t)(tx * B_DIM + b) * 2];
    __syncthreads();

#define AIDX(t_) ((size_t)((t_) * B_DIM + b) * (K_CAT / 2) + d)

#define LOADSLOT(FP_, ST_, tt_)                                                \
    { const int tc = (tt_) <= T_DIM - 1 ? (tt_) : T_DIM - 1;                   \
      FP_ = A32[AIDX(tc)];                                                     \
      ST_ = TT[(size_t)tc * D_DIM + d]; }

    // bank A: t % 8 in 0..3;  bank B: t % 8 in 4..7
    unsigned f0, f1, f2, f3, f4, f5, f6, f7;
    float4   t0, t1, t2, t3, t4, t5, t6, t7;

    LOADSLOT(f0, t0, 0)  LOADSLOT(f1, t1, 1)
    LOADSLOT(f2, t2, 2)  LOADSLOT(f3, t3, 3)
    LOADSLOT(f4, t4, 4)  LOADSLOT(f5, t5, 5)
    LOADSLOT(f6, t6, 6)  LOADSLOT(f7, t7, 7)

    // pre-init (1,1): with gate=0 at t=0 the generic select reproduces the
    // reference's t=0 rule exactly.
    float pAr = 1.f, pAi = 1.f, pBr = 1.f, pBi = 1.f;

#define ITER(tt_, FP_, ST_)                                                    \
    {                                                                          \
        const int t_ = (tt_);                                                  \
        float fr = h2f((unsigned short)(FP_ & 0xffffu));                       \
        float fi = h2f((unsigned short)(FP_ >> 16));                           \
        const bool isA = qm_s[t_] > 0.5f;                                      \
        const float cp = isA ? ST_.x : ST_.z;                                  \
        const float sp = isA ? ST_.y : ST_.w;                                  \
        const float pr = isA ? pAr : pBr;                                      \
        const float pi = isA ? pAi : pBi;                                      \
        const float tr = pr * cp - pi * sp;                                    \
        const float ti = pr * sp + pi * cp;                                    \
        const float gate = (t_ == 0) ? 0.0f : 1.0f;                            \
        const float m2 = fmaxf(tr * tr + ti * ti, 1e-30f);                     \
        const float inv = gate * __builtin_amdgcn_rsqf(m2);                    \
        fr += tr * inv;                                                        \
        fi += ti * inv;                                                        \
        pAr = isA ? fr : pAr;  pAi = isA ? fi : pAi;                           \
        pBr = isA ? pBr : fr;  pBi = isA ? pBi : fi;                           \
        A32[AIDX(t_)] = (unsigned)f2bf(fr) | ((unsigned)f2bf(fi) << 16);       \
    }

    // main loop: 13 groups of 8 (t = 0..103). Burst refills read t+8..t+15,
    // which this thread has NOT yet overwritten (still f16 from feat pass).
    for (int g = 0; g < 104; g += 8) {
        ITER(g + 0, f0, t0)
        ITER(g + 1, f1, t1)
        ITER(g + 2, f2, t2)
        ITER(g + 3, f3, t3)
        LOADSLOT(f0, t0, g + 8)
        LOADSLOT(f1, t1, g + 9)
        LOADSLOT(f2, t2, g + 10)
        LOADSLOT(f3, t3, g + 11)
        __builtin_amdgcn_sched_barrier(0x387);   // VMEM may not cross

        ITER(g + 4, f4, t4)
        ITER(g + 5, f5, t5)
        ITER(g + 6, f6, t6)
        ITER(g + 7, f7, t7)
        LOADSLOT(f4, t4, g + 12)
        LOADSLOT(f5, t5, g + 13)
        LOADSLOT(f6, t6, g + 14)
        LOADSLOT(f7, t7, g + 15)
        __builtin_amdgcn_sched_barrier(0x387);
    }
    // epilogue: bank A holds t=104..107; bank B slots 0,1 hold t=108,109
    // (slots 2,3 are clamped duplicates, never consumed).
    ITER(104, f0, t0)
    ITER(105, f1, t1)
    ITER(106, f2, t2)
    ITER(107, f3, t3)
    ITER(108, f4, t4)
    ITER(109, f5, t5)
#undef ITER
#undef LOADSLOT
#undef AIDX
}

// ---------------- kernel 3: bf16 MFMA GEMM  C = A @ Bt^T + bias ---------------
// Proven 1-phase m97 structure (~30 us = its structural ceiling for 29.5
// GFLOP): 128x128 tile, BK=64, global_load_lds width-16 into linear LDS
// (32 KB), 4 waves (2x2), 4x4 frags of 16x16x32.
#define BM 128
#define BN 128
#define BK 64

__global__ __launch_bounds__(256) void gemm_kernel(
    const unsigned short* __restrict__ A,
    const unsigned short* __restrict__ Bt,
    const float* __restrict__ bias2,
    float* __restrict__ C)
{
    __shared__ __align__(16) unsigned short As[BM * BK];   // 16 KB, linear
    __shared__ __align__(16) unsigned short Bs[BN * BK];   // 16 KB, linear

    const int tid = threadIdx.x;
    const int wave = tid >> 6;
    const int lane = tid & 63;
    const int wr = wave >> 1;          // 0..1 (M dir)
    const int wc = wave & 1;           // 0..1 (N dir)
    const int m0 = blockIdx.x * BM;
    const int n0 = blockIdx.y * BN;
    const int lrow = lane & 15;
    const int lk8 = (lane >> 4) * 8;   // k-offset of this lane's 8 elements

    const int srow = wave * 32;        // first row this wave stages
    const int lrow8 = lane >> 3;       // row within 8-row group
    const int lchunk = lane & 7;       // 16B chunk within row

    f32x4 acc[4][4] = {};

    for (int k0 = 0; k0 < K_CAT; k0 += BK) {
        #pragma unroll
        for (int c = 0; c < 4; ++c) {
            const int row = srow + c * 8 + lrow8;
            {
                const unsigned short* gp = A + (size_t)(m0 + row) * K_CAT + k0 + lchunk * 8;
                unsigned short* lp = As + (srow + c * 8) * BK + lane * 8;
                __builtin_amdgcn_global_load_lds(
                    (const __attribute__((address_space(1))) unsigned int*)gp,
                    (__attribute__((address_space(3))) unsigned int*)lp,
                    16, 0, 0);
            }
            {
                const unsigned short* gp = Bt + (size_t)(n0 + row) * K_CAT + k0 + lchunk * 8;
                unsigned short* lp = Bs + (srow + c * 8) * BK + lane * 8;
                __builtin_amdgcn_global_load_lds(
                    (const __attribute__((address_space(1))) unsigned int*)gp,
                    (__attribute__((address_space(3))) unsigned int*)lp,
                    16, 0, 0);
            }
        }
        __syncthreads();

        bf16x8 af[4][2], bfv[4][2];
        #pragma unroll
        for (int m = 0; m < 4; ++m)
            #pragma unroll
            for (int kk = 0; kk < 2; ++kk)
                af[m][kk] = *reinterpret_cast<const bf16x8*>(
                    &As[(wr * 64 + m * 16 + lrow) * BK + kk * 32 + lk8]);
        #pragma unroll
        for (int n = 0; n < 4; ++n)
            #pragma unroll
            for (int kk = 0; kk < 2; ++kk)
                bfv[n][kk] = *reinterpret_cast<const bf16x8*>(
                    &Bs[(wc * 64 + n * 16 + lrow) * BK + kk * 32 + lk8]);

        #pragma unroll
        for (int kk = 0; kk < 2; ++kk)
            #pragma unroll
            for (int m = 0; m < 4; ++m)
                #pragma unroll
                for (int n = 0; n < 4; ++n)
                    acc[m][n] = __builtin_amdgcn_mfma_f32_16x16x32_bf16(
                        af[m][kk], bfv[n][kk], acc[m][n], 0, 0, 0);
        __syncthreads();
    }

    // -------- epilogue: C/D layout col=lane&15, row=(lane>>4)*4+r  (m89/m91)
    const int rbase = m0 + wr * 64 + (lane >> 4) * 4;
    const int cbase = n0 + wc * 64;
    #pragma unroll
    for (int n = 0; n < 4; ++n) {
        const int col = cbase + n * 16 + lrow;
        const float bv = bias2[col];
        #pragma unroll
        for (int m = 0; m < 4; ++m) {
            const int row0 = rbase + m * 16;
            #pragma unroll
            for (int r = 0; r < 4; ++r) {
                C[(size_t)(row0 + r) * H_DIM + col] = acc[m][n][r] + bv;
            }
        }
    }
}

// ---------------- launcher ----------------
extern "C" void kernel_launch(void* const* d_in, const int* in_sizes, int n_in,
                              void* d_out, int out_size, void* d_ws, size_t ws_size,
                              hipStream_t stream) {
    const float* a      = (const float*)d_in[0];
    const float* v      = (const float*)d_in[1];
    const float* l      = (const float*)d_in[2];
    const float* qmask  = (const float*)d_in[3];
    // d_in[4] umask: unused by reference
    const float* mu_a   = (const float*)d_in[5];
    const float* mu_v   = (const float*)d_in[6];
    const float* mu_l   = (const float*)d_in[7];
    const float* shifta = (const float*)d_in[8];
    const float* shiftv = (const float*)d_in[9];
    const float* turna  = (const float*)d_in[10];
    const float* turnb  = (const float*)d_in[11];
    const float* W1     = (const float*)d_in[12];
    const float* b1     = (const float*)d_in[13];
    const float* W2     = (const float*)d_in[14];
    // d_in[15] b2: cancels in xr+xi
    float* out = (float*)d_out;

    char* ws = (char*)d_ws;
    unsigned short* Afeat = (unsigned short*)ws;                       // M*K_CAT bf16
    size_t offB  = (size_t)M_DIM * K_CAT * sizeof(unsigned short);     // 57.7 MB
    unsigned short* Bt = (unsigned short*)(ws + offB);                 // H*K_CAT bf16
    size_t offBias = offB + (size_t)H_DIM * K_CAT * sizeof(unsigned short);
    float* bias2 = (float*)(ws + offBias);
    size_t offTT = offBias + 4096;
    float4* TT = (float4*)(ws + offTT);                                // T*D float4

    prep_all_kernel<<<(H_DIM * K_CAT + 255) / 256, 256, 0, stream>>>(
        W1, b1, W2, turna, turnb, Bt, bias2, TT);
    feat_kernel<<<(M_DIM * D_DIM / 4) / 256, 256, 0, stream>>>(
        a, v, l, mu_a, mu_v, mu_l, shifta, shiftv, (unsigned int*)Afeat);
    scan_kernel<<<B_DIM * 2, 256, 0, stream>>>(
        qmask, TT, (unsigned int*)Afeat);
    dim3 grid(M_DIM / BM, H_DIM / BN);
    gemm_kernel<<<grid, 256, 0, stream>>>(Afeat, Bt, bias2, out);
}

// Round 18
// 122.852 us; speedup vs baseline: 1.1587x; 1.0069x over previous
//
#include <hip/hip_runtime.h>

// ---------------- problem constants (fixed by reference) ----------------
#define T_DIM 110
#define B_DIM 256
#define D_DIM 512
#define H_DIM 512
#define K_CAT 1024              // K layout: interleaved (fr0,fi0,fr1,fi1,...)
#define M_DIM (T_DIM * B_DIM)   // 28160
#define BD    (B_DIM * D_DIM)   // 131072

typedef float f32x4 __attribute__((ext_vector_type(4)));
typedef short bf16x8 __attribute__((ext_vector_type(8)));

static __device__ __forceinline__ unsigned short f2bf(float f) {
    unsigned u = __builtin_bit_cast(unsigned, f);
    u += 0x7fffu + ((u >> 16) & 1u);      // round-to-nearest-even
    return (unsigned short)(u >> 16);
}
static __device__ __forceinline__ unsigned short f2h(float f) {
    return __builtin_bit_cast(unsigned short, (_Float16)f);   // v_cvt_f16_f32 RNE
}
static __device__ __forceinline__ float h2f(unsigned short h) {
    return (float)__builtin_bit_cast(_Float16, h);
}

// ---------------- kernel 1: fused prep (weights + bias + turn table) ----------
__global__ __launch_bounds__(256) void prep_all_kernel(
    const float* __restrict__ W1, const float* __restrict__ b1,
    const float* __restrict__ W2,
    const float* __restrict__ turna, const float* __restrict__ turnb,
    unsigned short* __restrict__ Bt,   // [H][K_CAT] bf16
    float* __restrict__ bias2,         // [H]
    float4* __restrict__ TT)           // [T][D]
{
    int i = blockIdx.x * 256 + threadIdx.x;
    if (i < H_DIM) bias2[i] = 2.0f * b1[i];
    if (i < T_DIM * D_DIM) {
        float s1, c1, s2, c2;
        __sincosf(turna[i], &s1, &c1);
        __sincosf(turnb[i], &s2, &c2);
        TT[i] = make_float4(c1, s1, c2, s2);
    }
    if (i < H_DIM * K_CAT) {
        int h = i / K_CAT;
        int k = i % K_CAT;
        int j = k >> 1;
        float w = (k & 1) ? (W1[h * D_DIM + j] - W2[h * D_DIM + j])
                          : (W1[h * D_DIM + j] + W2[h * D_DIM + j]);
        Bt[i] = f2bf(w);
    }
}

// ---------------- kernel 2a: features -> A32 as f16 pairs (MLP-maximized) ------
// R17 post-mortem: VGPR=16 -> compiler serialized to ~1 outstanding load/wave
// -> 2.1 TB/s MLP-starved (Little's law). Fix: each thread owns 4 positions
// spaced Q = M*D/16 apart (Q%128==0 -> same d4, one shift load), issues ALL
// 12 float4 loads up front (48 VGPRs forced live), sched_barrier(0x387) pins
// them above the compute. launch_bounds(256,1) frees the register budget.
// Per-element numerics identical to R16/R17 (absmax 0.0596).
#define QPOS (M_DIM * D_DIM / 16)   // 901120 float4-positions per quarter

__global__ __launch_bounds__(256, 1) void feat_kernel(
    const float* __restrict__ a, const float* __restrict__ v,
    const float* __restrict__ l,
    const float* __restrict__ mu_a, const float* __restrict__ mu_v,
    const float* __restrict__ mu_l,
    const float* __restrict__ shifta, const float* __restrict__ shiftv,
    unsigned int* __restrict__ A32)    // [M][512] dwords
{
    const int tid = blockIdx.x * 256 + threadIdx.x;   // 0 .. QPOS-1 (exact grid)
    const int row0 = tid >> 7;                        // QPOS>>7 = 7040 rows/quarter
    const int d4   = (tid & 127) << 2;

    // ---- issue ALL 12 main loads up front (perfectly coalesced per wave) ----
    float4 A[4], V[4], L[4];
    #pragma unroll
    for (int k = 0; k < 4; ++k) {
        const size_t g = (size_t)(row0 + k * 7040) * D_DIM + d4;
        A[k] = *reinterpret_cast<const float4*>(a + g);
        V[k] = *reinterpret_cast<const float4*>(v + g);
        L[k] = *reinterpret_cast<const float4*>(l + g);
    }
    const float4 sa = *reinterpret_cast<const float4*>(shifta + d4);
    const float4 sv = *reinterpret_cast<const float4*>(shiftv + d4);
    float ma[4], mv[4], ml[4];
    #pragma unroll
    for (int k = 0; k < 4; ++k) {
        const int t = (row0 + k * 7040) >> 8;
        ma[k] = mu_a[t]; mv[k] = mu_v[t]; ml[k] = mu_l[t];
    }
    __builtin_amdgcn_sched_barrier(0x387);   // loads may not sink below here

    // ---- compute + store per position ----
    #pragma unroll
    for (int k = 0; k < 4; ++k) {
        const float aj[4] = {A[k].x, A[k].y, A[k].z, A[k].w};
        const float vj[4] = {V[k].x, V[k].y, V[k].z, V[k].w};
        const float lj[4] = {L[k].x, L[k].y, L[k].z, L[k].w};
        const float saj[4] = {sa.x, sa.y, sa.z, sa.w};
        const float svj[4] = {sv.x, sv.y, sv.z, sv.w};
        unsigned outw[4];
        #pragma unroll
        for (int j = 0; j < 4; ++j) {
            float sA, cA, sV, cV, sL, cL;
            __sincosf(aj[j] + saj[j], &sA, &cA);
            __sincosf(vj[j] + svj[j], &sV, &cV);
            __sincosf(lj[j],          &sL, &cL);
            const float fr = ml[k] * cL + ma[k] * cA + mv[k] * cV;
            const float fi = ml[k] * sL + ma[k] * sA + mv[k] * sV;
            outw[j] = (unsigned)f2h(fr) | ((unsigned)f2h(fi) << 16);
        }
        uint4 o = make_uint4(outw[0], outw[1], outw[2], outw[3]);
        *reinterpret_cast<uint4*>(
            A32 + (size_t)(row0 + k * 7040) * (K_CAT / 2) + d4) = o;
    }
}

// ---------------- kernel 2b: scan (serial over t), IN PLACE on A32 -------------
// (R16 version, verbatim — passed at absmax 0.0596, ~20 us.)
__global__ __launch_bounds__(256, 1) void scan_kernel(
    const float* __restrict__ qmask,
    const float4* __restrict__ TT,
    unsigned int* __restrict__ A32)
{
    __shared__ float qm_s[T_DIM];
    const int tx = threadIdx.x;
    const int b  = blockIdx.x >> 1;
    const int d  = ((blockIdx.x & 1) << 8) + tx;
    if (tx < T_DIM) qm_s[tx] = qmask[(size_t)(tx * B_DIM + b) * 2];
    __syncthreads();

#define AIDX(t_) ((size_t)((t_) * B_DIM + b) * (K_CAT / 2) + d)

#define LOADSLOT(FP_, ST_, tt_)                                                \
    { const int tc = (tt_) <= T_DIM - 1 ? (tt_) : T_DIM - 1;                   \
      FP_ = A32[AIDX(tc)];                                                     \
      ST_ = TT[(size_t)tc * D_DIM + d]; }

    // bank A: t % 8 in 0..3;  bank B: t % 8 in 4..7
    unsigned f0, f1, f2, f3, f4, f5, f6, f7;
    float4   t0, t1, t2, t3, t4, t5, t6, t7;

    LOADSLOT(f0, t0, 0)  LOADSLOT(f1, t1, 1)
    LOADSLOT(f2, t2, 2)  LOADSLOT(f3, t3, 3)
    LOADSLOT(f4, t4, 4)  LOADSLOT(f5, t5, 5)
    LOADSLOT(f6, t6, 6)  LOADSLOT(f7, t7, 7)

    // pre-init (1,1): with gate=0 at t=0 the generic select reproduces the
    // reference's t=0 rule exactly.
    float pAr = 1.f, pAi = 1.f, pBr = 1.f, pBi = 1.f;

#define ITER(tt_, FP_, ST_)                                                    \
    {                                                                          \
        const int t_ = (tt_);                                                  \
        float fr = h2f((unsigned short)(FP_ & 0xffffu));                       \
        float fi = h2f((unsigned short)(FP_ >> 16));                           \
        const bool isA = qm_s[t_] > 0.5f;                                      \
        const float cp = isA ? ST_.x : ST_.z;                                  \
        const float sp = isA ? ST_.y : ST_.w;                                  \
        const float pr = isA ? pAr : pBr;                                      \
        const float pi = isA ? pAi : pBi;                                      \
        const float tr = pr * cp - pi * sp;                                    \
        const float ti = pr * sp + pi * cp;                                    \
        const float gate = (t_ == 0) ? 0.0f : 1.0f;                            \
        const float m2 = fmaxf(tr * tr + ti * ti, 1e-30f);                     \
        const float inv = gate * __builtin_amdgcn_rsqf(m2);                    \
        fr += tr * inv;                                                        \
        fi += ti * inv;                                                        \
        pAr = isA ? fr : pAr;  pAi = isA ? fi : pAi;                           \
        pBr = isA ? pBr : fr;  pBi = isA ? pBi : fi;                           \
        A32[AIDX(t_)] = (unsigned)f2bf(fr) | ((unsigned)f2bf(fi) << 16);       \
    }

    // main loop: 13 groups of 8 (t = 0..103). Burst refills read t+8..t+15,
    // which this thread has NOT yet overwritten (still f16 from feat pass).
    for (int g = 0; g < 104; g += 8) {
        ITER(g + 0, f0, t0)
        ITER(g + 1, f1, t1)
        ITER(g + 2, f2, t2)
        ITER(g + 3, f3, t3)
        LOADSLOT(f0, t0, g + 8)
        LOADSLOT(f1, t1, g + 9)
        LOADSLOT(f2, t2, g + 10)
        LOADSLOT(f3, t3, g + 11)
        __builtin_amdgcn_sched_barrier(0x387);   // VMEM may not cross

        ITER(g + 4, f4, t4)
        ITER(g + 5, f5, t5)
        ITER(g + 6, f6, t6)
        ITER(g + 7, f7, t7)
        LOADSLOT(f4, t4, g + 12)
        LOADSLOT(f5, t5, g + 13)
        LOADSLOT(f6, t6, g + 14)
        LOADSLOT(f7, t7, g + 15)
        __builtin_amdgcn_sched_barrier(0x387);
    }
    // epilogue: bank A holds t=104..107; bank B slots 0,1 hold t=108,109
    // (slots 2,3 are clamped duplicates, never consumed).
    ITER(104, f0, t0)
    ITER(105, f1, t1)
    ITER(106, f2, t2)
    ITER(107, f3, t3)
    ITER(108, f4, t4)
    ITER(109, f5, t5)
#undef ITER
#undef LOADSLOT
#undef AIDX
}

// ---------------- kernel 3: bf16 MFMA GEMM  C = A @ Bt^T + bias ---------------
// Proven 1-phase m97 structure (~30 us structural ceiling for 29.5 GFLOP).
#define BM 128
#define BN 128
#define BK 64

__global__ __launch_bounds__(256) void gemm_kernel(
    const unsigned short* __restrict__ A,
    const unsigned short* __restrict__ Bt,
    const float* __restrict__ bias2,
    float* __restrict__ C)
{
    __shared__ __align__(16) unsigned short As[BM * BK];   // 16 KB, linear
    __shared__ __align__(16) unsigned short Bs[BN * BK];   // 16 KB, linear

    const int tid = threadIdx.x;
    const int wave = tid >> 6;
    const int lane = tid & 63;
    const int wr = wave >> 1;          // 0..1 (M dir)
    const int wc = wave & 1;           // 0..1 (N dir)
    const int m0 = blockIdx.x * BM;
    const int n0 = blockIdx.y * BN;
    const int lrow = lane & 15;
    const int lk8 = (lane >> 4) * 8;   // k-offset of this lane's 8 elements

    const int srow = wave * 32;        // first row this wave stages
    const int lrow8 = lane >> 3;       // row within 8-row group
    const int lchunk = lane & 7;       // 16B chunk within row

    f32x4 acc[4][4] = {};

    for (int k0 = 0; k0 < K_CAT; k0 += BK) {
        #pragma unroll
        for (int c = 0; c < 4; ++c) {
            const int row = srow + c * 8 + lrow8;
            {
                const unsigned short* gp = A + (size_t)(m0 + row) * K_CAT + k0 + lchunk * 8;
                unsigned short* lp = As + (srow + c * 8) * BK + lane * 8;
                __builtin_amdgcn_global_load_lds(
                    (const __attribute__((address_space(1))) unsigned int*)gp,
                    (__attribute__((address_space(3))) unsigned int*)lp,
                    16, 0, 0);
            }
            {
                const unsigned short* gp = Bt + (size_t)(n0 + row) * K_CAT + k0 + lchunk * 8;
                unsigned short* lp = Bs + (srow + c * 8) * BK + lane * 8;
                __builtin_amdgcn_global_load_lds(
                    (const __attribute__((address_space(1))) unsigned int*)gp,
                    (__attribute__((address_space(3))) unsigned int*)lp,
                    16, 0, 0);
            }
        }
        __syncthreads();

        bf16x8 af[4][2], bfv[4][2];
        #pragma unroll
        for (int m = 0; m < 4; ++m)
            #pragma unroll
            for (int kk = 0; kk < 2; ++kk)
                af[m][kk] = *reinterpret_cast<const bf16x8*>(
                    &As[(wr * 64 + m * 16 + lrow) * BK + kk * 32 + lk8]);
        #pragma unroll
        for (int n = 0; n < 4; ++n)
            #pragma unroll
            for (int kk = 0; kk < 2; ++kk)
                bfv[n][kk] = *reinterpret_cast<const bf16x8*>(
                    &Bs[(wc * 64 + n * 16 + lrow) * BK + kk * 32 + lk8]);

        #pragma unroll
        for (int kk = 0; kk < 2; ++kk)
            #pragma unroll
            for (int m = 0; m < 4; ++m)
                #pragma unroll
                for (int n = 0; n < 4; ++n)
                    acc[m][n] = __builtin_amdgcn_mfma_f32_16x16x32_bf16(
                        af[m][kk], bfv[n][kk], acc[m][n], 0, 0, 0);
        __syncthreads();
    }

    // -------- epilogue: C/D layout col=lane&15, row=(lane>>4)*4+r  (m89/m91)
    const int rbase = m0 + wr * 64 + (lane >> 4) * 4;
    const int cbase = n0 + wc * 64;
    #pragma unroll
    for (int n = 0; n < 4; ++n) {
        const int col = cbase + n * 16 + lrow;
        const float bv = bias2[col];
        #pragma unroll
        for (int m = 0; m < 4; ++m) {
            const int row0 = rbase + m * 16;
            #pragma unroll
            for (int r = 0; r < 4; ++r) {
                C[(size_t)(row0 + r) * H_DIM + col] = acc[m][n][r] + bv;
            }
        }
    }
}

// ---------------- launcher ----------------
extern "C" void kernel_launch(void* const* d_in, const int* in_sizes, int n_in,
                              void* d_out, int out_size, void* d_ws, size_t ws_size,
                              hipStream_t stream) {
    const float* a      = (const float*)d_in[0];
    const float* v      = (const float*)d_in[1];
    const float* l      = (const float*)d_in[2];
    const float* qmask  = (const float*)d_in[3];
    // d_in[4] umask: unused by reference
    const float* mu_a   = (const float*)d_in[5];
    const float* mu_v   = (const float*)d_in[6];
    const float* mu_l   = (const float*)d_in[7];
    const float* shifta = (const float*)d_in[8];
    const float* shiftv = (const float*)d_in[9];
    const float* turna  = (const float*)d_in[10];
    const float* turnb  = (const float*)d_in[11];
    const float* W1     = (const float*)d_in[12];
    const float* b1     = (const float*)d_in[13];
    const float* W2     = (const float*)d_in[14];
    // d_in[15] b2: cancels in xr+xi
    float* out = (float*)d_out;

    char* ws = (char*)d_ws;
    unsigned short* Afeat = (unsigned short*)ws;                       // M*K_CAT bf16
    size_t offB  = (size_t)M_DIM * K_CAT * sizeof(unsigned short);     // 57.7 MB
    unsigned short* Bt = (unsigned short*)(ws + offB);                 // H*K_CAT bf16
    size_t offBias = offB + (size_t)H_DIM * K_CAT * sizeof(unsigned short);
    float* bias2 = (float*)(ws + offBias);
    size_t offTT = offBias + 4096;
    float4* TT = (float4*)(ws + offTT);                                // T*D float4

    prep_all_kernel<<<(H_DIM * K_CAT + 255) / 256, 256, 0, stream>>>(
        W1, b1, W2, turna, turnb, Bt, bias2, TT);
    feat_kernel<<<QPOS / 256, 256, 0, stream>>>(
        a, v, l, mu_a, mu_v, mu_l, shifta, shiftv, (unsigned int*)Afeat);
    scan_kernel<<<B_DIM * 2, 256, 0, stream>>>(
        qmask, TT, (unsigned int*)Afeat);
    dim3 grid(M_DIM / BM, H_DIM / BN);
    gemm_kernel<<<grid, 256, 0, stream>>>(Afeat, Bt, bias2, out);
}

// Round 19
// 110.133 us; speedup vs baseline: 1.2925x; 1.1155x over previous
//
#include <hip/hip_runtime.h>

// ---------------- problem constants (fixed by reference) ----------------
#define T_DIM 110
#define B_DIM 256
#define D_DIM 512
#define H_DIM 512
#define K_CAT 1024              // K layout: interleaved (fr0,fi0,fr1,fi1,...)
#define M_DIM (T_DIM * B_DIM)   // 28160
#define BD    (B_DIM * D_DIM)   // 131072

typedef float f32x4 __attribute__((ext_vector_type(4)));
typedef short bf16x8 __attribute__((ext_vector_type(8)));

static __device__ __forceinline__ unsigned short f2bf(float f) {
    unsigned u = __builtin_bit_cast(unsigned, f);
    u += 0x7fffu + ((u >> 16) & 1u);      // round-to-nearest-even
    return (unsigned short)(u >> 16);
}

// ---------------- kernel 1: fused prep (weights + bias + turn table) ----------
// Bt[h][2j] = (W1+W2)[h][j]; Bt[h][2j+1] = (W1-W2)[h][j]; bias = 2*b1
// (b2 cancels in xr+xi). TT[t][d] = (cos ta, sin ta, cos tb, sin tb).
__global__ __launch_bounds__(256) void prep_all_kernel(
    const float* __restrict__ W1, const float* __restrict__ b1,
    const float* __restrict__ W2,
    const float* __restrict__ turna, const float* __restrict__ turnb,
    unsigned short* __restrict__ Bt,   // [H][K_CAT] bf16
    float* __restrict__ bias2,         // [H]
    float4* __restrict__ TT)           // [T][D]
{
    int i = blockIdx.x * 256 + threadIdx.x;
    if (i < H_DIM) bias2[i] = 2.0f * b1[i];
    if (i < T_DIM * D_DIM) {
        float s1, c1, s2, c2;
        __sincosf(turna[i], &s1, &c1);
        __sincosf(turnb[i], &s2, &c2);
        TT[i] = make_float4(c1, s1, c2, s2);
    }
    if (i < H_DIM * K_CAT) {
        int h = i / K_CAT;
        int k = i % K_CAT;
        int j = k >> 1;
        float w = (k & 1) ? (W1[h * D_DIM + j] - W2[h * D_DIM + j])
                          : (W1[h * D_DIM + j] + W2[h * D_DIM + j]);
        Bt[i] = f2bf(w);
    }
}

// ---------------- kernel 2: fused features + scan -> A[M][K_CAT] bf16 ----------
// (R13 version, byte-identical — measured 72 us, absmax 0.03125; the split
// feat+scan alternative measured 61+18=79 us and is strictly worse.)
// Slot-static register ring depth 4, unroll 4; sched_barrier(0x387) blocks
// only VMEM from crossing iteration boundaries; rsq(max(m2,1e-30)) replaces
// the IEEE divide (turn==0 stays exact: 0 * finite = 0).
__global__ __launch_bounds__(256, 1) void feat_scan_kernel(
    const float* __restrict__ a, const float* __restrict__ v,
    const float* __restrict__ l, const float* __restrict__ qmask,
    const float* __restrict__ mu_a, const float* __restrict__ mu_v,
    const float* __restrict__ mu_l,
    const float* __restrict__ shifta, const float* __restrict__ shiftv,
    const float4* __restrict__ TT,
    unsigned int* __restrict__ A32)    // [M][K_CAT/2] dwords (fr|fi<<16)
{
    __shared__ float qm_s[T_DIM], mua_s[T_DIM], muv_s[T_DIM], mul_s[T_DIM];
    const int tx = threadIdx.x;
    const int b  = blockIdx.x >> 1;
    const int d  = ((blockIdx.x & 1) << 8) + tx;
    if (tx < T_DIM) {
        qm_s[tx]  = qmask[(size_t)(tx * B_DIM + b) * 2];
        mua_s[tx] = mu_a[tx];
        muv_s[tx] = mu_v[tx];
        mul_s[tx] = mu_l[tx];
    }
    const float sa = shifta[d];
    const float sv = shiftv[d];
    __syncthreads();

    const size_t gbase = (size_t)b * D_DIM + d;

    // ---- prologue: fill the 4 slots (t = 0..3) ----
    float  s0a = a[gbase],                 s0v = v[gbase],
           s0l = l[gbase];
    float4 s0t = TT[d];
    float  s1a = a[(size_t)1 * BD + gbase], s1v = v[(size_t)1 * BD + gbase],
           s1l = l[(size_t)1 * BD + gbase];
    float4 s1t = TT[1 * D_DIM + d];
    float  s2a = a[(size_t)2 * BD + gbase], s2v = v[(size_t)2 * BD + gbase],
           s2l = l[(size_t)2 * BD + gbase];
    float4 s2t = TT[2 * D_DIM + d];
    float  s3a = a[(size_t)3 * BD + gbase], s3v = v[(size_t)3 * BD + gbase],
           s3l = l[(size_t)3 * BD + gbase];
    float4 s3t = TT[3 * D_DIM + d];

    // pre-init (1,1): with gate=0 at t=0 the generic select reproduces the
    // reference's t=0 rule exactly.
    float pAr = 1.f, pAi = 1.f, pBr = 1.f, pBi = 1.f;

#define ITER(tt_, SA_, SV_, SL_, ST_)                                          \
    {                                                                          \
        const int t_ = (tt_);                                                  \
        const float qa = qm_s[t_], ma = mua_s[t_],                             \
                    mv = muv_s[t_], ml = mul_s[t_];                            \
        float sA, cA, sV, cV, sL, cL;                                          \
        __sincosf(SA_ + sa, &sA, &cA);                                         \
        __sincosf(SV_ + sv, &sV, &cV);                                         \
        __sincosf(SL_,      &sL, &cL);                                         \
        float fr = ml * cL + ma * cA + mv * cV;                                \
        float fi = ml * sL + ma * sA + mv * sV;                                \
        const bool isA = qa > 0.5f;                                            \
        const float cp = isA ? ST_.x : ST_.z;                                  \
        const float sp = isA ? ST_.y : ST_.w;                                  \
        const float pr = isA ? pAr : pBr;                                      \
        const float pi = isA ? pAi : pBi;                                      \
        const float tr = pr * cp - pi * sp;                                    \
        const float ti = pr * sp + pi * cp;                                    \
        const float gate = (t_ == 0) ? 0.0f : 1.0f;                            \
        const float m2 = fmaxf(tr * tr + ti * ti, 1e-30f);                     \
        const float inv = gate * __builtin_amdgcn_rsqf(m2);                    \
        fr += tr * inv;                                                        \
        fi += ti * inv;                                                        \
        pAr = isA ? fr : pAr;  pAi = isA ? fi : pAi;                           \
        pBr = isA ? pBr : fr;  pBi = isA ? pBi : fi;                           \
        A32[(size_t)(t_ * B_DIM + b) * (K_CAT / 2) + d] =                      \
            (unsigned)f2bf(fr) | ((unsigned)f2bf(fi) << 16);                   \
        /* reload SAME slot for t+4 (clamped; tail dups harmless) */           \
        const int tnx = (t_ + 4 < T_DIM) ? t_ + 4 : T_DIM - 1;                 \
        SA_ = a[(size_t)tnx * BD + gbase];                                     \
        SV_ = v[(size_t)tnx * BD + gbase];                                     \
        SL_ = l[(size_t)tnx * BD + gbase];                                     \
        ST_ = TT[(size_t)tnx * D_DIM + d];                                     \
        /* directional fence: VMEM may not cross; VALU/SALU/DS may */          \
        __builtin_amdgcn_sched_barrier(0x387);                                 \
    }

    // 27 groups cover t = 0..107; peel 108 (slot0), 109 (slot1).
    for (int tb = 0; tb < 108; tb += 4) {
        ITER(tb,     s0a, s0v, s0l, s0t)
        ITER(tb + 1, s1a, s1v, s1l, s1t)
        ITER(tb + 2, s2a, s2v, s2l, s2t)
        ITER(tb + 3, s3a, s3v, s3l, s3t)
    }
    ITER(108, s0a, s0v, s0l, s0t)
    ITER(109, s1a, s1v, s1l, s1t)
#undef ITER
}

// ---------------- kernel 3: bf16 MFMA GEMM  C = A @ Bt^T + bias ---------------
// m97 1-phase structure with GRID AXES SWAPPED: blockIdx.x = N-tile (4,
// fast-varying) so the 4 blocks sharing one A-tile are dispatch-adjacent ->
// A-tile stays L2-resident (R10 counters showed FETCH 108.6 MB vs A's 57.7 MB
// = ~2x A re-read with the old M-fast order; GEMM is HBM-bound at ~5.6 TB/s,
// so the ~50 MB saved is ~8 us). Body unchanged: 128x128 tile, BK=64,
// global_load_lds width-16 into linear LDS (32 KB), 4 waves, 16x16x32 MFMA.
#define BM 128
#define BN 128
#define BK 64

__global__ __launch_bounds__(256) void gemm_kernel(
    const unsigned short* __restrict__ A,
    const unsigned short* __restrict__ Bt,
    const float* __restrict__ bias2,
    float* __restrict__ C)
{
    __shared__ __align__(16) unsigned short As[BM * BK];   // 16 KB, linear
    __shared__ __align__(16) unsigned short Bs[BN * BK];   // 16 KB, linear

    const int tid = threadIdx.x;
    const int wave = tid >> 6;
    const int lane = tid & 63;
    const int wr = wave >> 1;          // 0..1 (M dir)
    const int wc = wave & 1;           // 0..1 (N dir)
    const int m0 = blockIdx.y * BM;    // swapped: y = M-tile (220)
    const int n0 = blockIdx.x * BN;    // swapped: x = N-tile (4, fast)
    const int lrow = lane & 15;
    const int lk8 = (lane >> 4) * 8;   // k-offset of this lane's 8 elements

    const int srow = wave * 32;        // first row this wave stages
    const int lrow8 = lane >> 3;       // row within 8-row group
    const int lchunk = lane & 7;       // 16B chunk within row

    f32x4 acc[4][4] = {};

    for (int k0 = 0; k0 < K_CAT; k0 += BK) {
        #pragma unroll
        for (int c = 0; c < 4; ++c) {
            const int row = srow + c * 8 + lrow8;
            {
                const unsigned short* gp = A + (size_t)(m0 + row) * K_CAT + k0 + lchunk * 8;
                unsigned short* lp = As + (srow + c * 8) * BK + lane * 8;
                __builtin_amdgcn_global_load_lds(
                    (const __attribute__((address_space(1))) unsigned int*)gp,
                    (__attribute__((address_space(3))) unsigned int*)lp,
                    16, 0, 0);
            }
            {
                const unsigned short* gp = Bt + (size_t)(n0 + row) * K_CAT + k0 + lchunk * 8;
                unsigned short* lp = Bs + (srow + c * 8) * BK + lane * 8;
                __builtin_amdgcn_global_load_lds(
                    (const __attribute__((address_space(1))) unsigned int*)gp,
                    (__attribute__((address_space(3))) unsigned int*)lp,
                    16, 0, 0);
            }
        }
        __syncthreads();

        bf16x8 af[4][2], bfv[4][2];
        #pragma unroll
        for (int m = 0; m < 4; ++m)
            #pragma unroll
            for (int kk = 0; kk < 2; ++kk)
                af[m][kk] = *reinterpret_cast<const bf16x8*>(
                    &As[(wr * 64 + m * 16 + lrow) * BK + kk * 32 + lk8]);
        #pragma unroll
        for (int n = 0; n < 4; ++n)
            #pragma unroll
            for (int kk = 0; kk < 2; ++kk)
                bfv[n][kk] = *reinterpret_cast<const bf16x8*>(
                    &Bs[(wc * 64 + n * 16 + lrow) * BK + kk * 32 + lk8]);

        #pragma unroll
        for (int kk = 0; kk < 2; ++kk)
            #pragma unroll
            for (int m = 0; m < 4; ++m)
                #pragma unroll
                for (int n = 0; n < 4; ++n)
                    acc[m][n] = __builtin_amdgcn_mfma_f32_16x16x32_bf16(
                        af[m][kk], bfv[n][kk], acc[m][n], 0, 0, 0);
        __syncthreads();
    }

    // -------- epilogue: C/D layout col=lane&15, row=(lane>>4)*4+r  (m89/m91)
    const int rbase = m0 + wr * 64 + (lane >> 4) * 4;
    const int cbase = n0 + wc * 64;
    #pragma unroll
    for (int n = 0; n < 4; ++n) {
        const int col = cbase + n * 16 + lrow;
        const float bv = bias2[col];
        #pragma unroll
        for (int m = 0; m < 4; ++m) {
            const int row0 = rbase + m * 16;
            #pragma unroll
            for (int r = 0; r < 4; ++r) {
                C[(size_t)(row0 + r) * H_DIM + col] = acc[m][n][r] + bv;
            }
        }
    }
}

// ---------------- launcher ----------------
extern "C" void kernel_launch(void* const* d_in, const int* in_sizes, int n_in,
                              void* d_out, int out_size, void* d_ws, size_t ws_size,
                              hipStream_t stream) {
    const float* a      = (const float*)d_in[0];
    const float* v      = (const float*)d_in[1];
    const float* l      = (const float*)d_in[2];
    const float* qmask  = (const float*)d_in[3];
    // d_in[4] umask: unused by reference
    const float* mu_a   = (const float*)d_in[5];
    const float* mu_v   = (const float*)d_in[6];
    const float* mu_l   = (const float*)d_in[7];
    const float* shifta = (const float*)d_in[8];
    const float* shiftv = (const float*)d_in[9];
    const float* turna  = (const float*)d_in[10];
    const float* turnb  = (const float*)d_in[11];
    const float* W1     = (const float*)d_in[12];
    const float* b1     = (const float*)d_in[13];
    const float* W2     = (const float*)d_in[14];
    // d_in[15] b2: cancels in xr+xi
    float* out = (float*)d_out;

    char* ws = (char*)d_ws;
    unsigned short* Afeat = (unsigned short*)ws;                       // M*K_CAT bf16
    size_t offB  = (size_t)M_DIM * K_CAT * sizeof(unsigned short);     // 57.7 MB
    unsigned short* Bt = (unsigned short*)(ws + offB);                 // H*K_CAT bf16
    size_t offBias = offB + (size_t)H_DIM * K_CAT * sizeof(unsigned short);
    float* bias2 = (float*)(ws + offBias);
    size_t offTT = offBias + 4096;
    float4* TT = (float4*)(ws + offTT);                                // T*D float4

    prep_all_kernel<<<(H_DIM * K_CAT + 255) / 256, 256, 0, stream>>>(
        W1, b1, W2, turna, turnb, Bt, bias2, TT);
    feat_scan_kernel<<<B_DIM * 2, 256, 0, stream>>>(
        a, v, l, qmask, mu_a, mu_v, mu_l, shifta, shiftv, TT, (unsigned int*)Afeat);
    dim3 grid(H_DIM / BN, M_DIM / BM);     // x = N-tiles (4, fast), y = M-tiles
    gemm_kernel<<<grid, 256, 0, stream>>>(Afeat, Bt, bias2, out);
}